// Round 1
// baseline (786.208 us; speedup 1.0000x reference)
//
#include <hip/hip_runtime.h>
#include <hip/hip_bf16.h>
#include <math.h>

#define T_TOTAL   262144
#define DIN       512
#define DMODEL    256
#define TYPE_EMB_ 32
#define NSCAL     8
#define KMAX      64
#define ZDIM      (DIN + NSCAL + TYPE_EMB_)   // 552
#define CONF_TH_  0.3f
#define EPS_      1e-6f
#define FPB       256                          // frames per block, kernel 1

// out layout (floats): tokens [0,16384) | mask [16384,16448) | type [16448,16512)
//                      conf [16512,16576) | s_k [16576,17088)
#define OFF_MASK  16384
#define OFF_TYPE  16448
#define OFF_CONF  16512
#define OFF_SK    16576

// ---------------- kernel 1: per-segment feature sums ----------------
__global__ __launch_bounds__(256) void k1_feat_sums(
    const float* __restrict__ features,
    const int*   __restrict__ seg_start,
    const int*   __restrict__ seg_end,
    float*       __restrict__ acc /* [KMAX][DIN] */)
{
    __shared__ float4 part[128];
    const int tid = threadIdx.x;
    const int c4  = tid & 127;   // float4 column 0..127
    const int r   = tid >> 7;    // row parity 0/1
    const int w0  = blockIdx.x * FPB;
    const int w1  = w0 + FPB;

    // largest k with seg_start[k] <= w0  (== segment containing w0)
    int lo = 0, hi = KMAX - 1;
    while (lo < hi) {
        int mid = (lo + hi + 1) >> 1;
        if (seg_start[mid] <= w0) lo = mid; else hi = mid - 1;
    }
    int k = lo;

    const float4* __restrict__ f4 = (const float4*)features;

    for (;;) {
        const int s = max(w0, seg_start[k]);
        const int e = min(w1, seg_end[k]);

        float4 a0 = make_float4(0.f, 0.f, 0.f, 0.f);
        float4 a1 = make_float4(0.f, 0.f, 0.f, 0.f);
        int t = s + r;
        for (; t + 2 < e; t += 4) {            // two outstanding loads
            float4 x0 = f4[(size_t)t       * 128 + c4];
            float4 x1 = f4[(size_t)(t + 2) * 128 + c4];
            a0.x += x0.x; a0.y += x0.y; a0.z += x0.z; a0.w += x0.w;
            a1.x += x1.x; a1.y += x1.y; a1.z += x1.z; a1.w += x1.w;
        }
        if (t < e) {
            float4 x0 = f4[(size_t)t * 128 + c4];
            a0.x += x0.x; a0.y += x0.y; a0.z += x0.z; a0.w += x0.w;
        }
        a0.x += a1.x; a0.y += a1.y; a0.z += a1.z; a0.w += a1.w;

        // fold r=1 into r=0 via LDS, then one atomicAdd set per column
        if (r == 1) part[c4] = a0;
        __syncthreads();
        if (r == 0) {
            float4 p = part[c4];
            a0.x += p.x; a0.y += p.y; a0.z += p.z; a0.w += p.w;
            float* dst = acc + (size_t)k * DIN + c4 * 4;
            atomicAdd(dst + 0, a0.x);
            atomicAdd(dst + 1, a0.y);
            atomicAdd(dst + 2, a0.z);
            atomicAdd(dst + 3, a0.w);
        }
        if (seg_end[k] >= w1 || k == KMAX - 1) break;
        ++k;
        __syncthreads();   // part[] reuse
    }
}

// ---------------- reductions ----------------
__device__ inline float waveSum(float v) {
    #pragma unroll
    for (int off = 32; off > 0; off >>= 1) v += __shfl_down(v, off, 64);
    return v;
}
__device__ inline float waveMax(float v) {
    #pragma unroll
    for (int off = 32; off > 0; off >>= 1) v = fmaxf(v, __shfl_down(v, off, 64));
    return v;
}

// ---------------- kernel 2: per-segment scalar stats -> out ----------------
__global__ __launch_bounds__(256) void k2_scalars(
    const float* __restrict__ energy,
    const float* __restrict__ frame_conf,
    const float* __restrict__ stream_conf,
    const int*   __restrict__ seg_start,
    const int*   __restrict__ seg_end,
    const int*   __restrict__ event_type_id,
    const void*  __restrict__ fps_ptr,
    float*       __restrict__ out)
{
    __shared__ float red[6][4];
    const int k    = blockIdx.x;
    const int tid  = threadIdx.x;
    const int lane = tid & 63;
    const int wid  = tid >> 6;
    const int s = seg_start[k];
    const int e = seg_end[k];

    float sum_e = 0.f, sum_c = 0.f, v0 = 0.f, v1 = 0.f, v2 = 0.f, pk = -1e30f;
    for (int t = s + tid; t < e; t += 256) {
        float en = energy[t];
        sum_e += en;
        pk = fmaxf(pk, en);
        sum_c += frame_conf[t];
        v0 += stream_conf[3 * t + 0];
        v1 += stream_conf[3 * t + 1];
        v2 += stream_conf[3 * t + 2];
    }
    sum_e = waveSum(sum_e); sum_c = waveSum(sum_c);
    v0 = waveSum(v0); v1 = waveSum(v1); v2 = waveSum(v2);
    pk = waveMax(pk);
    if (lane == 0) {
        red[0][wid] = sum_e; red[1][wid] = sum_c; red[2][wid] = v0;
        red[3][wid] = v1;    red[4][wid] = v2;    red[5][wid] = pk;
    }
    __syncthreads();
    if (tid == 0) {
        float t0=0,t1=0,t2=0,t3=0,t4=0,t5=-1e30f;
        #pragma unroll
        for (int i = 0; i < 4; ++i) {
            t0 += red[0][i]; t1 += red[1][i]; t2 += red[2][i];
            t3 += red[3][i]; t4 += red[4][i]; t5 = fmaxf(t5, red[5][i]);
        }
        red[0][0]=t0; red[1][0]=t1; red[2][0]=t2; red[3][0]=t3; red[4][0]=t4; red[5][0]=t5;
    }
    __syncthreads();
    const float tot_e = red[0][0];
    __syncthreads();

    // pass 2: entropy
    float ent = 0.f;
    const float inv_tot = 1.f / (tot_e + EPS_);
    for (int t = s + tid; t < e; t += 256) {
        float p = energy[t] * inv_tot;
        ent += p * logf(p + EPS_);
    }
    ent = waveSum(ent);
    if (lane == 0) red[0][wid] = ent;
    __syncthreads();

    if (tid == 0) {
        float entropy = -(red[0][0] + red[0][1] + red[0][2] + red[0][3]);
        const float len = (float)(e - s);
        const float inv_len = 1.f / len;

        // decode fps (python scalar: int32 expected, tolerate float32 bits)
        int bits = *(const int*)fps_ptr;
        float fps = (bits > 0 && bits < 1000000) ? (float)bits : *(const float*)fps_ptr;

        float conf        = red[1][0] * inv_len;
        float mean_motion = tot_e * inv_len;
        float peak        = red[5][0];
        float vis0 = red[2][0] * inv_len;
        float vis1 = red[3][0] * inv_len;
        float vis2 = red[4][0] * inv_len;
        float dur  = len / fps;
        float lat  = (float)s / fps;

        float sv[8] = {dur, lat, mean_motion, peak, entropy, vis0, vis1, vis2};
        #pragma unroll
        for (int j = 0; j < 8; ++j) out[OFF_SK + k * 8 + j] = log1pf(sv[j]);
        out[OFF_CONF + k] = conf;
        out[OFF_MASK + k] = (conf >= CONF_TH_) ? 1.f : 0.f;
        out[OFF_TYPE + k] = (float)event_type_id[k];
    }
}

// ---------------- kernel 3: tokens = z @ W^T + bias ----------------
__global__ __launch_bounds__(256) void k3_tokens(
    const float* __restrict__ acc,        // [KMAX][DIN] feature sums
    const int*   __restrict__ seg_start,
    const int*   __restrict__ seg_end,
    const int*   __restrict__ event_type_id,
    const float* __restrict__ emb,        // [16][32]
    const float* __restrict__ W,          // [256][552]
    const float* __restrict__ bias,       // [256]
    const float* __restrict__ out_sk,     // out + OFF_SK
    float*       __restrict__ tokens)     // out + 0
{
    __shared__ __align__(16) float z[ZDIM];  // 552
    const int k   = blockIdx.x;
    const int tid = threadIdx.x;
    const float inv_len = 1.f / (float)(seg_end[k] - seg_start[k]);

    for (int j = tid; j < DIN; j += 256) z[j] = acc[(size_t)k * DIN + j] * inv_len;
    if (tid < NSCAL) {
        z[DIN + tid] = out_sk[k * 8 + tid];
    } else if (tid >= 32 && tid < 32 + TYPE_EMB_) {
        z[DIN + NSCAL + (tid - 32)] = emb[event_type_id[k] * TYPE_EMB_ + (tid - 32)];
    }
    __syncthreads();

    const float4* z4 = (const float4*)z;
    const float4* w4 = (const float4*)(W + (size_t)tid * ZDIM);  // byte off = 2208*tid, 16B-aligned
    float a = bias[tid];
    #pragma unroll 2
    for (int j = 0; j < ZDIM / 4; ++j) {
        float4 x = z4[j];
        float4 w = w4[j];
        a += x.x * w.x + x.y * w.y + x.z * w.z + x.w * w.w;
    }
    tokens[k * DMODEL + tid] = a;
}

extern "C" void kernel_launch(void* const* d_in, const int* in_sizes, int n_in,
                              void* d_out, int out_size, void* d_ws, size_t ws_size,
                              hipStream_t stream) {
    const float* features    = (const float*)d_in[0];
    const float* energy      = (const float*)d_in[1];
    const float* frame_conf  = (const float*)d_in[2];
    const float* stream_conf = (const float*)d_in[3];
    const int*   seg_start   = (const int*)d_in[4];
    const int*   seg_end     = (const int*)d_in[5];
    const int*   type_id     = (const int*)d_in[6];
    const float* emb         = (const float*)d_in[7];
    const float* W           = (const float*)d_in[8];
    const float* bias        = (const float*)d_in[9];
    const void*  fps         = d_in[10];
    float* out = (float*)d_out;
    float* acc = (float*)d_ws;   // 64*512 floats = 128 KB

    hipMemsetAsync(acc, 0, (size_t)KMAX * DIN * sizeof(float), stream);
    k1_feat_sums<<<T_TOTAL / FPB, 256, 0, stream>>>(features, seg_start, seg_end, acc);
    k2_scalars<<<KMAX, 256, 0, stream>>>(energy, frame_conf, stream_conf,
                                         seg_start, seg_end, type_id, fps, out);
    k3_tokens<<<KMAX, 256, 0, stream>>>(acc, seg_start, seg_end, type_id,
                                        emb, W, bias, out + OFF_SK, out);
}

// Round 2
// 741.826 us; speedup vs baseline: 1.0598x; 1.0598x over previous
//
#include <hip/hip_runtime.h>
#include <hip/hip_bf16.h>
#include <math.h>

#define T_TOTAL   262144
#define DIN       512
#define DMODEL    256
#define TYPE_EMB_ 32
#define NSCAL     8
#define KMAX      64
#define ZDIM      (DIN + NSCAL + TYPE_EMB_)   // 552
#define CONF_TH_  0.3f
#define EPS_      1e-6f
#define FPB       256                          // frames per block, kernel 1

// out layout (floats): tokens [0,16384) | mask | type | conf | s_k
#define OFF_MASK  16384
#define OFF_TYPE  16448
#define OFF_CONF  16512
#define OFF_SK    16576

// ws layout (floats): acc[64][512] | scal[64][8] = {sum_e, sum_elog, sum_conf, v0, v1, v2, peak_bits, pad}
#define SCAL_OFF  (KMAX * DIN)

__device__ inline float waveSum(float v) {
    #pragma unroll
    for (int off = 32; off > 0; off >>= 1) v += __shfl_down(v, off, 64);
    return v;
}
__device__ inline float waveMax(float v) {
    #pragma unroll
    for (int off = 32; off > 0; off >>= 1) v = fmaxf(v, __shfl_down(v, off, 64));
    return v;
}

// ------- kernel 1: fused feature sums + scalar-stream stats (one pass) -------
__global__ __launch_bounds__(256) void k1_fused(
    const float* __restrict__ features,
    const float* __restrict__ energy,
    const float* __restrict__ frame_conf,
    const float* __restrict__ stream_conf,
    const int*   __restrict__ seg_start,
    const int*   __restrict__ seg_end,
    float*       __restrict__ ws)
{
    __shared__ float4 part[128];
    __shared__ float  red[7][4];
    const int tid  = threadIdx.x;
    const int c4   = tid & 127;   // float4 column 0..127
    const int r    = tid >> 7;    // row parity 0/1
    const int lane = tid & 63;
    const int wid  = tid >> 6;
    const int w0   = blockIdx.x * FPB;
    const int w1   = w0 + FPB;

    // largest k with seg_start[k] <= w0
    int lo = 0, hi = KMAX - 1;
    while (lo < hi) {
        int mid = (lo + hi + 1) >> 1;
        if (seg_start[mid] <= w0) lo = mid; else hi = mid - 1;
    }
    const int k0 = lo;
    const bool single = (seg_end[k0] >= w1);   // window fully inside one segment (common)

    const float4* __restrict__ f4 = (const float4*)features;

    // ---------------- feature-sum phase ----------------
    if (single) {
        float4 a0 = make_float4(0.f,0.f,0.f,0.f), a1 = a0, a2 = a0, a3 = a0;
        int t = w0 + r;
        #pragma unroll 1
        for (int i = 0; i < 32; ++i, t += 8) {   // 4 loads in flight
            float4 x0 = f4[(size_t)(t)     * 128 + c4];
            float4 x1 = f4[(size_t)(t + 2) * 128 + c4];
            float4 x2 = f4[(size_t)(t + 4) * 128 + c4];
            float4 x3 = f4[(size_t)(t + 6) * 128 + c4];
            a0.x += x0.x; a0.y += x0.y; a0.z += x0.z; a0.w += x0.w;
            a1.x += x1.x; a1.y += x1.y; a1.z += x1.z; a1.w += x1.w;
            a2.x += x2.x; a2.y += x2.y; a2.z += x2.z; a2.w += x2.w;
            a3.x += x3.x; a3.y += x3.y; a3.z += x3.z; a3.w += x3.w;
        }
        a0.x += a1.x + a2.x + a3.x; a0.y += a1.y + a2.y + a3.y;
        a0.z += a1.z + a2.z + a3.z; a0.w += a1.w + a2.w + a3.w;
        if (r == 1) part[c4] = a0;
        __syncthreads();
        if (r == 0) {
            float4 p = part[c4];
            a0.x += p.x; a0.y += p.y; a0.z += p.z; a0.w += p.w;
            float* dst = ws + (size_t)k0 * DIN + c4 * 4;
            atomicAdd(dst + 0, a0.x);
            atomicAdd(dst + 1, a0.y);
            atomicAdd(dst + 2, a0.z);
            atomicAdd(dst + 3, a0.w);
        }
    } else {
        int k = k0;
        for (;;) {
            const int s = max(w0, seg_start[k]);
            const int e = min(w1, seg_end[k]);
            float4 a0 = make_float4(0.f,0.f,0.f,0.f), a1 = a0;
            int t = s + r;
            for (; t + 2 < e; t += 4) {
                float4 x0 = f4[(size_t)t       * 128 + c4];
                float4 x1 = f4[(size_t)(t + 2) * 128 + c4];
                a0.x += x0.x; a0.y += x0.y; a0.z += x0.z; a0.w += x0.w;
                a1.x += x1.x; a1.y += x1.y; a1.z += x1.z; a1.w += x1.w;
            }
            if (t < e) {
                float4 x0 = f4[(size_t)t * 128 + c4];
                a0.x += x0.x; a0.y += x0.y; a0.z += x0.z; a0.w += x0.w;
            }
            a0.x += a1.x; a0.y += a1.y; a0.z += a1.z; a0.w += a1.w;
            if (r == 1) part[c4] = a0;
            __syncthreads();
            if (r == 0) {
                float4 p = part[c4];
                a0.x += p.x; a0.y += p.y; a0.z += p.z; a0.w += p.w;
                float* dst = ws + (size_t)k * DIN + c4 * 4;
                atomicAdd(dst + 0, a0.x);
                atomicAdd(dst + 1, a0.y);
                atomicAdd(dst + 2, a0.z);
                atomicAdd(dst + 3, a0.w);
            }
            if (seg_end[k] >= w1 || k == KMAX - 1) break;
            ++k;
            __syncthreads();   // part[] reuse
        }
    }

    // ---------------- scalar-stream phase (one frame per thread) ----------------
    int k = k0;
    for (;;) {
        const int s = max(w0, seg_start[k]);
        const int e = min(w1, seg_end[k]);
        float se = 0.f, sl = 0.f, sc = 0.f, v0 = 0.f, v1 = 0.f, v2 = 0.f, pk = 0.f;
        const int t = s + tid;
        if (t < e) {
            float en = energy[t];
            se = en;
            sl = en * logf(en + 1e-12f);   // sum e*log(e); entropy reconstructed later
            pk = en;
            sc = frame_conf[t];
            v0 = stream_conf[3 * t + 0];
            v1 = stream_conf[3 * t + 1];
            v2 = stream_conf[3 * t + 2];
        }
        se = waveSum(se); sl = waveSum(sl); sc = waveSum(sc);
        v0 = waveSum(v0); v1 = waveSum(v1); v2 = waveSum(v2);
        pk = waveMax(pk);
        if (lane == 0) {
            red[0][wid] = se; red[1][wid] = sl; red[2][wid] = sc;
            red[3][wid] = v0; red[4][wid] = v1; red[5][wid] = v2;
            red[6][wid] = pk;
        }
        __syncthreads();
        float* scal = ws + SCAL_OFF + k * 8;
        if (tid < 6) {
            float v = red[tid][0] + red[tid][1] + red[tid][2] + red[tid][3];
            atomicAdd(scal + tid, v);
        } else if (tid == 6) {
            float m = fmaxf(fmaxf(red[6][0], red[6][1]), fmaxf(red[6][2], red[6][3]));
            atomicMax((int*)(scal + 6), __float_as_int(m));   // energy >= 0: bit order == value order
        }
        if (seg_end[k] >= w1 || k == KMAX - 1) break;
        ++k;
        __syncthreads();   // red[] reuse
    }
}

// ------- kernel 2: finalize s_k/conf/mask/type + tokens = z @ W^T + bias -------
__global__ __launch_bounds__(256) void k2_final(
    const float* __restrict__ ws,
    const int*   __restrict__ seg_start,
    const int*   __restrict__ seg_end,
    const int*   __restrict__ event_type_id,
    const float* __restrict__ emb,        // [16][32]
    const float* __restrict__ W,          // [256][552]
    const float* __restrict__ bias,       // [256]
    const void*  __restrict__ fps_ptr,
    float*       __restrict__ out)
{
    __shared__ __align__(16) float z[ZDIM];
    __shared__ float skv[8];
    const int k   = blockIdx.x;
    const int tid = threadIdx.x;
    const int s = seg_start[k], e = seg_end[k];
    const float len = (float)(e - s);
    const float inv_len = 1.f / len;

    if (tid == 0) {
        const float* scal = ws + SCAL_OFF + k * 8;
        const float S  = scal[0];
        const float SL = scal[1];
        const float C  = scal[2];
        const float V0 = scal[3], V1 = scal[4], V2 = scal[5];
        const float pk = __int_as_float(((const int*)scal)[6]);
        const float denom = S + EPS_;
        // -sum p*log p  with p = e/(S+eps):  log(denom)*(S/denom) - SL/denom
        const float entropy = logf(denom) * (S / denom) - SL / denom;

        int bits = *(const int*)fps_ptr;
        float fps = (bits > 0 && bits < 1000000) ? (float)bits : *(const float*)fps_ptr;

        const float conf = C * inv_len;
        float sv[8] = {len / fps, (float)s / fps, S * inv_len, pk, entropy,
                       V0 * inv_len, V1 * inv_len, V2 * inv_len};
        #pragma unroll
        for (int j = 0; j < 8; ++j) {
            float t = log1pf(sv[j]);
            skv[j] = t;
            out[OFF_SK + k * 8 + j] = t;
        }
        out[OFF_CONF + k] = conf;
        out[OFF_MASK + k] = (conf >= CONF_TH_) ? 1.f : 0.f;
        out[OFF_TYPE + k] = (float)event_type_id[k];
    }
    for (int j = tid; j < DIN; j += 256) z[j] = ws[(size_t)k * DIN + j] * inv_len;
    __syncthreads();
    if (tid < NSCAL) {
        z[DIN + tid] = skv[tid];
    } else if (tid >= 32 && tid < 32 + TYPE_EMB_) {
        z[DIN + NSCAL + (tid - 32)] = emb[event_type_id[k] * TYPE_EMB_ + (tid - 32)];
    }
    __syncthreads();

    const float4* z4 = (const float4*)z;
    const float4* w4 = (const float4*)(W + (size_t)tid * ZDIM);  // 2208 B row stride, 16B-aligned
    float a = bias[tid];
    #pragma unroll 2
    for (int j = 0; j < ZDIM / 4; ++j) {
        float4 x = z4[j];
        float4 w = w4[j];
        a += x.x * w.x + x.y * w.y + x.z * w.z + x.w * w.w;
    }
    out[k * DMODEL + tid] = a;
}

extern "C" void kernel_launch(void* const* d_in, const int* in_sizes, int n_in,
                              void* d_out, int out_size, void* d_ws, size_t ws_size,
                              hipStream_t stream) {
    const float* features    = (const float*)d_in[0];
    const float* energy      = (const float*)d_in[1];
    const float* frame_conf  = (const float*)d_in[2];
    const float* stream_conf = (const float*)d_in[3];
    const int*   seg_start   = (const int*)d_in[4];
    const int*   seg_end     = (const int*)d_in[5];
    const int*   type_id     = (const int*)d_in[6];
    const float* emb         = (const float*)d_in[7];
    const float* W           = (const float*)d_in[8];
    const float* bias        = (const float*)d_in[9];
    const void*  fps         = d_in[10];
    float* out = (float*)d_out;
    float* ws  = (float*)d_ws;

    hipMemsetAsync(ws, 0, (size_t)(KMAX * DIN + KMAX * 8) * sizeof(float), stream);
    k1_fused<<<T_TOTAL / FPB, 256, 0, stream>>>(features, energy, frame_conf, stream_conf,
                                                seg_start, seg_end, ws);
    k2_final<<<KMAX, 256, 0, stream>>>(ws, seg_start, seg_end, type_id,
                                       emb, W, bias, fps, out);
}

// Round 4
// 735.467 us; speedup vs baseline: 1.0690x; 1.0086x over previous
//
#include <hip/hip_runtime.h>
#include <hip/hip_bf16.h>
#include <math.h>

#define T_TOTAL   262144
#define DIN       512
#define DMODEL    256
#define TYPE_EMB_ 32
#define NSCAL     8
#define KMAX      64
#define ZDIM      (DIN + NSCAL + TYPE_EMB_)   // 552
#define CONF_TH_  0.3f
#define EPS_      1e-6f
#define FPB       256                          // frames per block, kernel 1

// out layout (floats): tokens [0,16384) | mask | type | conf | s_k
#define OFF_MASK  16384
#define OFF_TYPE  16448
#define OFF_CONF  16512
#define OFF_SK    16576

// ws layout (floats): acc[64][512] | scal[64][8] = {sum_e, sum_elog, sum_conf, v0, v1, v2, peak_bits, pad}
#define SCAL_OFF  (KMAX * DIN)

__device__ inline float waveSum(float v) {
    #pragma unroll
    for (int off = 32; off > 0; off >>= 1) v += __shfl_down(v, off, 64);
    return v;
}
__device__ inline float waveMax(float v) {
    #pragma unroll
    for (int off = 32; off > 0; off >>= 1) v = fmaxf(v, __shfl_down(v, off, 64));
    return v;
}
__device__ inline void acc4(float4& a, const float4& b) {
    a.x += b.x; a.y += b.y; a.z += b.z; a.w += b.w;
}

// ------- kernel 1: fused feature sums + scalar-stream stats (one pass) -------
__global__ __launch_bounds__(256) void k1_fused(
    const float* __restrict__ features,
    const float* __restrict__ energy,
    const float* __restrict__ frame_conf,
    const float* __restrict__ stream_conf,
    const int*   __restrict__ seg_start,
    const int*   __restrict__ seg_end,
    float*       __restrict__ ws)
{
    __shared__ float4 part[128];
    __shared__ float  red[7][4];
    const int tid  = threadIdx.x;
    const int c4   = tid & 127;   // float4 column 0..127
    const int r    = tid >> 7;    // row parity 0/1
    const int lane = tid & 63;
    const int wid  = tid >> 6;
    const int w0   = blockIdx.x * FPB;
    const int w1   = w0 + FPB;

    // largest k with seg_start[k] <= w0
    int lo = 0, hi = KMAX - 1;
    while (lo < hi) {
        int mid = (lo + hi + 1) >> 1;
        if (seg_start[mid] <= w0) lo = mid; else hi = mid - 1;
    }
    const int k0 = lo;
    const bool single = (seg_end[k0] >= w1);   // window fully inside one segment (common)

    const float4* __restrict__ f4 = (const float4*)features;

    if (single) {
        // -------- prefetch scalar streams (results consumed after feature loop) --------
        const int tf = w0 + tid;               // always inside [s,e) in single path
        const float en  = energy[tf];
        const float fc  = frame_conf[tf];
        const float sv0 = stream_conf[3 * tf + 0];
        const float sv1 = stream_conf[3 * tf + 1];
        const float sv2 = stream_conf[3 * tf + 2];

        // -------- feature-sum phase: 8 loads in flight --------
        float4 a0 = make_float4(0.f,0.f,0.f,0.f);
        float4 a1 = a0, a2 = a0, a3 = a0, a4 = a0, a5 = a0, a6 = a0, a7 = a0;
        int t = w0 + r;
        #pragma unroll 1
        for (int i = 0; i < 16; ++i, t += 16) {
            float4 x0 = f4[(size_t)(t)      * 128 + c4];
            float4 x1 = f4[(size_t)(t + 2)  * 128 + c4];
            float4 x2 = f4[(size_t)(t + 4)  * 128 + c4];
            float4 x3 = f4[(size_t)(t + 6)  * 128 + c4];
            float4 x4 = f4[(size_t)(t + 8)  * 128 + c4];
            float4 x5 = f4[(size_t)(t + 10) * 128 + c4];
            float4 x6 = f4[(size_t)(t + 12) * 128 + c4];
            float4 x7 = f4[(size_t)(t + 14) * 128 + c4];
            acc4(a0, x0); acc4(a1, x1); acc4(a2, x2); acc4(a3, x3);
            acc4(a4, x4); acc4(a5, x5); acc4(a6, x6); acc4(a7, x7);
        }
        acc4(a0, a4); acc4(a1, a5); acc4(a2, a6); acc4(a3, a7);
        acc4(a0, a1); acc4(a2, a3); acc4(a0, a2);
        if (r == 1) part[c4] = a0;
        __syncthreads();
        if (r == 0) {
            float4 p = part[c4];
            acc4(a0, p);
            float* dst = ws + (size_t)k0 * DIN + c4 * 4;
            atomicAdd(dst + 0, a0.x);
            atomicAdd(dst + 1, a0.y);
            atomicAdd(dst + 2, a0.z);
            atomicAdd(dst + 3, a0.w);
        }

        // -------- scalar phase: data already in registers --------
        float se = waveSum(en);
        float sl = waveSum(en * logf(en + 1e-12f));
        float sc = waveSum(fc);
        float v0 = waveSum(sv0);
        float v1 = waveSum(sv1);
        float v2 = waveSum(sv2);
        float pk = waveMax(en);
        if (lane == 0) {
            red[0][wid] = se; red[1][wid] = sl; red[2][wid] = sc;
            red[3][wid] = v0; red[4][wid] = v1; red[5][wid] = v2;
            red[6][wid] = pk;
        }
        __syncthreads();
        float* scal = ws + SCAL_OFF + k0 * 8;
        if (tid < 6) {
            atomicAdd(scal + tid, red[tid][0] + red[tid][1] + red[tid][2] + red[tid][3]);
        } else if (tid == 6) {
            float m = fmaxf(fmaxf(red[6][0], red[6][1]), fmaxf(red[6][2], red[6][3]));
            atomicMax((int*)(scal + 6), __float_as_int(m));   // energy >= 0
        }
        return;
    }

    // ---------------- boundary path (rare: <7% of blocks) ----------------
    int k = k0;
    for (;;) {
        const int s = max(w0, seg_start[k]);
        const int e = min(w1, seg_end[k]);
        float4 a0 = make_float4(0.f,0.f,0.f,0.f), a1 = a0;
        int t = s + r;
        for (; t + 2 < e; t += 4) {
            float4 x0 = f4[(size_t)t       * 128 + c4];
            float4 x1 = f4[(size_t)(t + 2) * 128 + c4];
            acc4(a0, x0); acc4(a1, x1);
        }
        if (t < e) {
            float4 x0 = f4[(size_t)t * 128 + c4];
            acc4(a0, x0);
        }
        acc4(a0, a1);
        if (r == 1) part[c4] = a0;
        __syncthreads();
        if (r == 0) {
            float4 p = part[c4];
            acc4(a0, p);
            float* dst = ws + (size_t)k * DIN + c4 * 4;
            atomicAdd(dst + 0, a0.x);
            atomicAdd(dst + 1, a0.y);
            atomicAdd(dst + 2, a0.z);
            atomicAdd(dst + 3, a0.w);
        }
        if (seg_end[k] >= w1 || k == KMAX - 1) break;
        ++k;
        __syncthreads();   // part[] reuse
    }

    k = k0;
    for (;;) {
        const int s = max(w0, seg_start[k]);
        const int e = min(w1, seg_end[k]);
        float se = 0.f, sl = 0.f, sc = 0.f, v0 = 0.f, v1 = 0.f, v2 = 0.f, pk = 0.f;
        const int t = s + tid;
        if (t < e) {
            float en = energy[t];
            se = en;
            sl = en * logf(en + 1e-12f);
            pk = en;
            sc = frame_conf[t];
            v0 = stream_conf[3 * t + 0];
            v1 = stream_conf[3 * t + 1];
            v2 = stream_conf[3 * t + 2];
        }
        se = waveSum(se); sl = waveSum(sl); sc = waveSum(sc);
        v0 = waveSum(v0); v1 = waveSum(v1); v2 = waveSum(v2);
        pk = waveMax(pk);
        if (lane == 0) {
            red[0][wid] = se; red[1][wid] = sl; red[2][wid] = sc;
            red[3][wid] = v0; red[4][wid] = v1; red[5][wid] = v2;
            red[6][wid] = pk;
        }
        __syncthreads();
        float* scal = ws + SCAL_OFF + k * 8;
        if (tid < 6) {
            atomicAdd(scal + tid, red[tid][0] + red[tid][1] + red[tid][2] + red[tid][3]);
        } else if (tid == 6) {
            float m = fmaxf(fmaxf(red[6][0], red[6][1]), fmaxf(red[6][2], red[6][3]));
            atomicMax((int*)(scal + 6), __float_as_int(m));
        }
        if (seg_end[k] >= w1 || k == KMAX - 1) break;
        ++k;
        __syncthreads();   // red[] reuse
    }
}

// ------- kernel 2: finalize s_k/conf/mask/type + tokens = z @ W^T + bias -------
__global__ __launch_bounds__(256) void k2_final(
    const float* __restrict__ ws,
    const int*   __restrict__ seg_start,
    const int*   __restrict__ seg_end,
    const int*   __restrict__ event_type_id,
    const float* __restrict__ emb,        // [16][32]
    const float* __restrict__ W,          // [256][552]
    const float* __restrict__ bias,       // [256]
    const void*  __restrict__ fps_ptr,
    float*       __restrict__ out)
{
    __shared__ __align__(16) float z[ZDIM];
    __shared__ float skv[8];
    const int k   = blockIdx.x;
    const int tid = threadIdx.x;
    const int s = seg_start[k], e = seg_end[k];
    const float len = (float)(e - s);
    const float inv_len = 1.f / len;

    if (tid == 0) {
        const float* scal = ws + SCAL_OFF + k * 8;
        const float S  = scal[0];
        const float SL = scal[1];
        const float C  = scal[2];
        const float V0 = scal[3], V1 = scal[4], V2 = scal[5];
        const float pk = __int_as_float(((const int*)scal)[6]);
        const float denom = S + EPS_;
        // -sum p*log p  with p = e/(S+eps):  log(denom)*(S/denom) - SL/denom
        const float entropy = logf(denom) * (S / denom) - SL / denom;

        int bits = *(const int*)fps_ptr;
        float fps = (bits > 0 && bits < 1000000) ? (float)bits : *(const float*)fps_ptr;

        const float conf = C * inv_len;
        float sv[8] = {len / fps, (float)s / fps, S * inv_len, pk, entropy,
                       V0 * inv_len, V1 * inv_len, V2 * inv_len};
        #pragma unroll
        for (int j = 0; j < 8; ++j) {
            float t = log1pf(sv[j]);
            skv[j] = t;
            out[OFF_SK + k * 8 + j] = t;
        }
        out[OFF_CONF + k] = conf;
        out[OFF_MASK + k] = (conf >= CONF_TH_) ? 1.f : 0.f;
        out[OFF_TYPE + k] = (float)event_type_id[k];
    }
    for (int j = tid; j < DIN; j += 256) z[j] = ws[(size_t)k * DIN + j] * inv_len;
    __syncthreads();
    if (tid < NSCAL) {
        z[DIN + tid] = skv[tid];
    } else if (tid >= 32 && tid < 32 + TYPE_EMB_) {
        z[DIN + NSCAL + (tid - 32)] = emb[event_type_id[k] * TYPE_EMB_ + (tid - 32)];
    }
    __syncthreads();

    const float4* z4 = (const float4*)z;
    const float4* w4 = (const float4*)(W + (size_t)tid * ZDIM);  // 2208 B row stride, 16B-aligned
    float a = bias[tid];
    #pragma unroll 2
    for (int j = 0; j < ZDIM / 4; ++j) {
        float4 x = z4[j];
        float4 w = w4[j];
        a += x.x * w.x + x.y * w.y + x.z * w.z + x.w * w.w;
    }
    out[k * DMODEL + tid] = a;
}

extern "C" void kernel_launch(void* const* d_in, const int* in_sizes, int n_in,
                              void* d_out, int out_size, void* d_ws, size_t ws_size,
                              hipStream_t stream) {
    const float* features    = (const float*)d_in[0];
    const float* energy      = (const float*)d_in[1];
    const float* frame_conf  = (const float*)d_in[2];
    const float* stream_conf = (const float*)d_in[3];
    const int*   seg_start   = (const int*)d_in[4];
    const int*   seg_end     = (const int*)d_in[5];
    const int*   type_id     = (const int*)d_in[6];
    const float* emb         = (const float*)d_in[7];
    const float* W           = (const float*)d_in[8];
    const float* bias        = (const float*)d_in[9];
    const void*  fps         = d_in[10];
    float* out = (float*)d_out;
    float* ws  = (float*)d_ws;

    hipMemsetAsync(ws, 0, (size_t)(KMAX * DIN + KMAX * 8) * sizeof(float), stream);
    k1_fused<<<T_TOTAL / FPB, 256, 0, stream>>>(features, energy, frame_conf, stream_conf,
                                                seg_start, seg_end, ws);
    k2_final<<<KMAX, 256, 0, stream>>>(ws, seg_start, seg_end, type_id,
                                       emb, W, bias, fps, out);
}